// Round 8
// baseline (533.039 us; speedup 1.0000x reference)
//
#include <hip/hip_runtime.h>

#define N_PTS    700000
#define N_VOXELS 250000
#define M_SP     20000
#define EPS_BN   1e-4f
#define NB_V     245   // ceil(N_VOXELS/1024)
#define NB_S     20    // ceil(M_SP/1024)

typedef __attribute__((ext_vector_type(8))) short  bf16x8;
typedef __attribute__((ext_vector_type(8))) ushort u16x8;
typedef __attribute__((ext_vector_type(4))) float  f32x4;

__device__ __forceinline__ ushort f2bf(float f) {
    unsigned u = __float_as_uint(f);
    return (ushort)((u + 0x7FFFu + ((u >> 16) & 1u)) >> 16);
}
__device__ __forceinline__ float bf2f(ushort h) {
    return __uint_as_float(((unsigned)h) << 16);
}

// ================= CSR build (both segmentations in one sweep) =================
__global__ __launch_bounds__(256) void k_hist2(const int* __restrict__ p2v,
                                               const int* __restrict__ sp,
                                               int* __restrict__ cnt_v,
                                               int* __restrict__ cnt_s) {
    int i = blockIdx.x * 256 + threadIdx.x;
    if (i < N_PTS) {
        atomicAdd(&cnt_v[p2v[i]], 1);
        atomicAdd(&cnt_s[sp[i]], 1);
    }
}

// partial sums for BOTH cnt arrays (blocks [0,NB_V) -> v, [NB_V,NB_V+NB_S) -> s)
__global__ __launch_bounds__(256) void k_part2(const int* __restrict__ cnt_v,
                                               const int* __restrict__ cnt_s,
                                               int* __restrict__ psum_v,
                                               int* __restrict__ psum_s) {
    __shared__ int l[256];
    int b = blockIdx.x, t = threadIdx.x;
    const int* cnt; int* psum; int n, bb;
    if (b < NB_V) { cnt = cnt_v; psum = psum_v; n = N_VOXELS; bb = b; }
    else          { cnt = cnt_s; psum = psum_s; n = M_SP;     bb = b - NB_V; }
    int base = bb * 1024 + t * 4;
    int s = 0;
    #pragma unroll
    for (int j = 0; j < 4; ++j) { int i = base + j; if (i < n) s += cnt[i]; }
    l[t] = s; __syncthreads();
    for (int st = 128; st > 0; st >>= 1) {
        if (t < st) l[t] += l[t + st];
        __syncthreads();
    }
    if (t == 0) psum[bb] = l[0];
}

// exclusive scan of both psum arrays (block 0 -> v, block 1 -> s)
__global__ __launch_bounds__(256) void k_scan2(int* __restrict__ psum_v,
                                               int* __restrict__ psum_s) {
    __shared__ int l[256];
    int t = threadIdx.x;
    int* psum = blockIdx.x == 0 ? psum_v : psum_s;
    int nb    = blockIdx.x == 0 ? NB_V : NB_S;
    int orig = (t < nb) ? psum[t] : 0;
    l[t] = orig; __syncthreads();
    for (int st = 1; st < 256; st <<= 1) {
        int v = (t >= st) ? l[t - st] : 0;
        __syncthreads();
        l[t] += v;
        __syncthreads();
    }
    if (t < nb) psum[t] = l[t] - orig;
}

// chunk-local exclusive scan + base for both arrays
__global__ __launch_bounds__(256) void k_excl2(const int* __restrict__ cnt_v,
                                               const int* __restrict__ cnt_s,
                                               const int* __restrict__ psum_v,
                                               const int* __restrict__ psum_s,
                                               int* __restrict__ off_v,
                                               int* __restrict__ off_s,
                                               int* __restrict__ cur_v,
                                               int* __restrict__ cur_s) {
    __shared__ int l[256];
    int b = blockIdx.x, t = threadIdx.x;
    const int* cnt; const int* psum; int* off; int* cur; int n, bb;
    if (b < NB_V) { cnt = cnt_v; psum = psum_v; off = off_v; cur = cur_v; n = N_VOXELS; bb = b; }
    else          { cnt = cnt_s; psum = psum_s; off = off_s; cur = cur_s; n = M_SP;     bb = b - NB_V; }
    int base = bb * 1024 + t * 4;
    int c[4]; int s = 0;
    #pragma unroll
    for (int j = 0; j < 4; ++j) {
        int i = base + j;
        c[j] = (i < n) ? cnt[i] : 0;
        s += c[j];
    }
    int orig = s;
    l[t] = s; __syncthreads();
    for (int st = 1; st < 256; st <<= 1) {
        int v = (t >= st) ? l[t - st] : 0;
        __syncthreads();
        l[t] += v;
        __syncthreads();
    }
    int run = l[t] - orig + psum[bb];
    #pragma unroll
    for (int j = 0; j < 4; ++j) {
        int i = base + j;
        if (i < n) { off[i] = run; cur[i] = run; run += c[j]; }
    }
}

// fill: pidx_v gets point index (vox_gather reads feats[p]);
//       pidx_s gets VOXEL id directly (sp_gather skips the p2v indirection)
__global__ __launch_bounds__(256) void k_fill2(const int* __restrict__ p2v,
                                               const int* __restrict__ sp,
                                               int* __restrict__ cur_v,
                                               int* __restrict__ cur_s,
                                               int* __restrict__ pidx_v,
                                               int* __restrict__ pidx_s) {
    int i = blockIdx.x * 256 + threadIdx.x;
    if (i < N_PTS) {
        int pv = p2v[i];
        pidx_v[atomicAdd(&cur_v[pv], 1)] = i;
        pidx_s[atomicAdd(&cur_s[sp[i]], 1)] = pv;
    }
}

// ================= voxelization: CSR gather mean -> bf16 hi/lo (8ch padded) =================
__global__ __launch_bounds__(256) void k_vox_gather(const float* __restrict__ feats,
                                                    const int* __restrict__ off,
                                                    const int* __restrict__ cnt,
                                                    const int* __restrict__ pidx,
                                                    ushort* __restrict__ voxH,
                                                    ushort* __restrict__ voxL) {
    int v = blockIdx.x * 256 + threadIdx.x;
    if (v >= N_VOXELS) return;
    int s = off[v], c = cnt[v];
    float a[6] = {0, 0, 0, 0, 0, 0};
    for (int k = 0; k < c; ++k) {
        int p = pidx[s + k];
        const float2* f = (const float2*)(feats + (size_t)p * 6);
        float2 x0 = f[0], x1 = f[1], x2 = f[2];
        a[0] += x0.x; a[1] += x0.y; a[2] += x1.x;
        a[3] += x1.y; a[4] += x2.x; a[5] += x2.y;
    }
    float inv = 1.0f / (float)max(c, 1);
    u16x8 hv, lv;
    #pragma unroll
    for (int j = 0; j < 6; ++j) {
        float m = a[j] * inv;
        ushort h = f2bf(m);
        hv[j] = h;
        lv[j] = f2bf(m - bf2f(h));
    }
    hv[6] = 0; hv[7] = 0; lv[6] = 0; lv[7] = 0;
    *(u16x8*)(voxH + (size_t)v * 8) = hv;
    *(u16x8*)(voxL + (size_t)v * 8) = lv;
}

// ================= weight pre-pack: conv_in (hi/lo), K = 4 offsets x 8 ch =================
__global__ __launch_bounds__(256) void k_wprep_in(const float* __restrict__ W,
                                                  ushort* __restrict__ WbH,
                                                  ushort* __restrict__ WbL) {
    int t = blockIdx.x * 256 + threadIdx.x;
    if (t >= 7 * 2 * 64) return;
    int l  = t & 63;
    int nf = (t >> 6) & 1;
    int s7 = t >> 7;
    int g  = l >> 4;
    int c  = nf * 16 + (l & 15);
    int o  = s7 * 4 + g;
    u16x8 hv, lv;
    #pragma unroll
    for (int j = 0; j < 8; ++j) {
        float w = (j < 6 && o < 27) ? W[(o * 6 + j) * 32 + c] : 0.0f;
        ushort h = f2bf(w);
        hv[j] = h;
        lv[j] = f2bf(w - bf2f(h));
    }
    *(u16x8*)(WbH + (size_t)t * 8) = hv;
    *(u16x8*)(WbL + (size_t)t * 8) = lv;
}

// ================= weight pre-pack: conv32m bf16 B-frag order =================
__global__ __launch_bounds__(256) void k_wprep(const float* __restrict__ W,
                                               ushort* __restrict__ Wb) {
    int t = blockIdx.x * 256 + threadIdx.x;
    if (t >= 4 * 27 * 2 * 64) return;
    int l  = t & 63;
    int nf = (t >> 6) & 1;
    int co = t >> 7;
    const float* Wo = W + (size_t)co * 1024;
    int kb = (l >> 4) * 8;
    int c  = nf * 16 + (l & 15);
    u16x8 v;
    #pragma unroll
    for (int j = 0; j < 8; ++j) v[j] = f2bf(Wo[(kb + j) * 32 + c]);
    *(u16x8*)(Wb + (size_t)t * 8) = v;
}

// ================= input conv 6->32 via MFMA (hi/lo split, ~fp32 accurate) =================
// Branchless gathers (clamp + select-zero) + full unroll -> loads pipelined.
__global__ __launch_bounds__(256, 4) void k_conv_in_m(const ushort* __restrict__ voxH,
                                                      const ushort* __restrict__ voxL,
                                                      const int* __restrict__ nbr,
                                                      const ushort* __restrict__ WbH,
                                                      const ushort* __restrict__ WbL,
                                                      const float* __restrict__ gamma,
                                                      const float* __restrict__ beta,
                                                      float* __restrict__ x_out,
                                                      ushort* __restrict__ act_out) {
    __shared__ int nl[128][27];
    const int tid = threadIdx.x;
    const int vbase = blockIdx.x * 128;
    for (int i = tid; i < 128 * 27; i += 256) {
        int gi = vbase * 27 + i;
        nl[0][i] = (gi < N_VOXELS * 27) ? nbr[gi] : -1;
    }
    __syncthreads();

    const int l   = tid & 63;
    const int wav = tid >> 6;
    const int r   = l & 15;
    const int g   = l >> 4;
    const int vr0 = wav * 32 + r;
    const int vr1 = vr0 + 16;

    f32x4 a00 = {0,0,0,0}, a01 = {0,0,0,0}, a10 = {0,0,0,0}, a11 = {0,0,0,0};
    const bf16x8 zz = {0,0,0,0,0,0,0,0};

    #pragma unroll
    for (int s7 = 0; s7 < 7; ++s7) {
        int o = s7 * 4 + g;
        bool ok = (o < 27);
        int oc = ok ? o : 26;
        int n0 = nl[vr0][oc];
        int n1 = nl[vr1][oc];
        bool v0 = ok && (n0 >= 0);
        bool v1 = ok && (n1 >= 0);
        int s0 = max(n0, 0), s1 = max(n1, 0);
        bf16x8 A0h = *(const bf16x8*)(voxH + (size_t)s0 * 8);
        bf16x8 A0l = *(const bf16x8*)(voxL + (size_t)s0 * 8);
        bf16x8 A1h = *(const bf16x8*)(voxH + (size_t)s1 * 8);
        bf16x8 A1l = *(const bf16x8*)(voxL + (size_t)s1 * 8);
        A0h = v0 ? A0h : zz;  A0l = v0 ? A0l : zz;
        A1h = v1 ? A1h : zz;  A1l = v1 ? A1l : zz;
        const bf16x8 B0h = *(const bf16x8*)(WbH + (size_t)(s7 * 2 + 0) * 512 + l * 8);
        const bf16x8 B1h = *(const bf16x8*)(WbH + (size_t)(s7 * 2 + 1) * 512 + l * 8);
        const bf16x8 B0l = *(const bf16x8*)(WbL + (size_t)(s7 * 2 + 0) * 512 + l * 8);
        const bf16x8 B1l = *(const bf16x8*)(WbL + (size_t)(s7 * 2 + 1) * 512 + l * 8);
        // (Ah+Al)*Bh + Ah*Bl  ==  A*B to ~2^-17
        a00 = __builtin_amdgcn_mfma_f32_16x16x32_bf16(A0h, B0h, a00, 0, 0, 0);
        a00 = __builtin_amdgcn_mfma_f32_16x16x32_bf16(A0l, B0h, a00, 0, 0, 0);
        a00 = __builtin_amdgcn_mfma_f32_16x16x32_bf16(A0h, B0l, a00, 0, 0, 0);
        a01 = __builtin_amdgcn_mfma_f32_16x16x32_bf16(A0h, B1h, a01, 0, 0, 0);
        a01 = __builtin_amdgcn_mfma_f32_16x16x32_bf16(A0l, B1h, a01, 0, 0, 0);
        a01 = __builtin_amdgcn_mfma_f32_16x16x32_bf16(A0h, B1l, a01, 0, 0, 0);
        a10 = __builtin_amdgcn_mfma_f32_16x16x32_bf16(A1h, B0h, a10, 0, 0, 0);
        a10 = __builtin_amdgcn_mfma_f32_16x16x32_bf16(A1l, B0h, a10, 0, 0, 0);
        a10 = __builtin_amdgcn_mfma_f32_16x16x32_bf16(A1h, B0l, a10, 0, 0, 0);
        a11 = __builtin_amdgcn_mfma_f32_16x16x32_bf16(A1h, B1h, a11, 0, 0, 0);
        a11 = __builtin_amdgcn_mfma_f32_16x16x32_bf16(A1l, B1h, a11, 0, 0, 0);
        a11 = __builtin_amdgcn_mfma_f32_16x16x32_bf16(A1h, B1l, a11, 0, 0, 0);
    }

    const float rs  = rsqrtf(1.f + EPS_BN);
    const float sc0 = gamma[r] * rs,      bb0 = beta[r];
    const float sc1 = gamma[r + 16] * rs, bb1 = beta[r + 16];

    #pragma unroll
    for (int fr = 0; fr < 2; ++fr) {
        #pragma unroll
        for (int j = 0; j < 4; ++j) {
            int vv = vbase + wav * 32 + fr * 16 + g * 4 + j;
            if (vv >= N_VOXELS) continue;
            float v0 = fr ? a10[j] : a00[j];
            float v1 = fr ? a11[j] : a01[j];
            float* xp = x_out + (size_t)vv * 32;
            xp[r]      = v0;
            xp[r + 16] = v1;
            act_out[(size_t)vv * 32 + r]      = f2bf(fmaxf(v0 * sc0 + bb0, 0.f));
            act_out[(size_t)vv * 32 + r + 16] = f2bf(fmaxf(v1 * sc1 + bb1, 0.f));
        }
    }
}

// ================= 32->32 gather conv via bf16 MFMA =================
// Branchless gathers + full unroll of the 27-offset loop for latency hiding.
__global__ __launch_bounds__(256, 4) void k_conv32m(const ushort* __restrict__ act_in,
                                                    const int* __restrict__ nbr,
                                                    const ushort* __restrict__ Wb,
                                                    const float* __restrict__ gamma,
                                                    const float* __restrict__ beta,
                                                    float* __restrict__ x_inout,
                                                    ushort* __restrict__ act_out) {
    __shared__ int nl[128][27];
    const int tid = threadIdx.x;
    const int vbase = blockIdx.x * 128;
    for (int i = tid; i < 128 * 27; i += 256) {
        int gi = vbase * 27 + i;
        nl[0][i] = (gi < N_VOXELS * 27) ? nbr[gi] : -1;
    }
    __syncthreads();

    const int l   = tid & 63;
    const int wav = tid >> 6;
    const int r   = l & 15;
    const int g   = l >> 4;
    const int vr0 = wav * 32 + r;
    const int vr1 = vr0 + 16;

    f32x4 a00 = {0,0,0,0}, a01 = {0,0,0,0}, a10 = {0,0,0,0}, a11 = {0,0,0,0};
    const bf16x8 zz = {0,0,0,0,0,0,0,0};

    #pragma unroll
    for (int o = 0; o < 27; ++o) {
        int n0 = nl[vr0][o];
        int n1 = nl[vr1][o];
        int s0 = max(n0, 0), s1 = max(n1, 0);
        bf16x8 A0 = *(const bf16x8*)(act_in + (size_t)s0 * 32 + g * 8);
        bf16x8 A1 = *(const bf16x8*)(act_in + (size_t)s1 * 32 + g * 8);
        A0 = (n0 >= 0) ? A0 : zz;
        A1 = (n1 >= 0) ? A1 : zz;
        const bf16x8 B0 = *(const bf16x8*)(Wb + (size_t)(o * 2 + 0) * 512 + l * 8);
        const bf16x8 B1 = *(const bf16x8*)(Wb + (size_t)(o * 2 + 1) * 512 + l * 8);
        a00 = __builtin_amdgcn_mfma_f32_16x16x32_bf16(A0, B0, a00, 0, 0, 0);
        a01 = __builtin_amdgcn_mfma_f32_16x16x32_bf16(A0, B1, a01, 0, 0, 0);
        a10 = __builtin_amdgcn_mfma_f32_16x16x32_bf16(A1, B0, a10, 0, 0, 0);
        a11 = __builtin_amdgcn_mfma_f32_16x16x32_bf16(A1, B1, a11, 0, 0, 0);
    }

    const float rs  = rsqrtf(1.f + EPS_BN);
    const float sc0 = gamma[r] * rs,      bb0 = beta[r];
    const float sc1 = gamma[r + 16] * rs, bb1 = beta[r + 16];

    #pragma unroll
    for (int fr = 0; fr < 2; ++fr) {
        #pragma unroll
        for (int j = 0; j < 4; ++j) {
            int vv = vbase + wav * 32 + fr * 16 + g * 4 + j;
            if (vv >= N_VOXELS) continue;
            float v0 = fr ? a10[j] : a00[j];
            float v1 = fr ? a11[j] : a01[j];
            if (x_inout) {
                float* xp = x_inout + (size_t)vv * 32;
                v0 += xp[r];
                v1 += xp[r + 16];
                xp[r]      = v0;
                xp[r + 16] = v1;
            }
            act_out[(size_t)vv * 32 + r]      = f2bf(fmaxf(v0 * sc0 + bb0, 0.f));
            act_out[(size_t)vv * 32 + r + 16] = f2bf(fmaxf(v1 * sc1 + bb1, 0.f));
        }
    }
}

// ================= superpoint mean: CSR gather (wave per superpoint) =================
// pidx_s holds the VOXEL id per point (written by k_fill2) -> no p2v indirection.
__global__ __launch_bounds__(256) void k_sp_gather(const ushort* __restrict__ act,
                                                   const int* __restrict__ off,
                                                   const int* __restrict__ cnt,
                                                   const int* __restrict__ pidx,
                                                   float* __restrict__ out) {
    int sp = blockIdx.x * 4 + (threadIdx.x >> 6);
    if (sp >= M_SP) return;
    int l   = threadIdx.x & 63;
    int grp = l >> 4;
    int ch2 = l & 15;
    int s = off[sp], c = cnt[sp];
    float a0 = 0.f, a1 = 0.f;
    for (int j = s + grp; j < s + c; j += 4) {
        int v = pidx[j];
        unsigned pk = *(const unsigned*)(act + (size_t)v * 32 + ch2 * 2);
        a0 += __uint_as_float(pk << 16);
        a1 += __uint_as_float(pk & 0xFFFF0000u);
    }
    a0 += __shfl_xor(a0, 16); a1 += __shfl_xor(a1, 16);
    a0 += __shfl_xor(a0, 32); a1 += __shfl_xor(a1, 32);
    if (grp == 0) {
        float inv = 1.0f / (float)max(c, 1);
        *(float2*)(out + (size_t)sp * 32 + ch2 * 2) = make_float2(a0 * inv, a1 * inv);
    }
}

extern "C" void kernel_launch(void* const* d_in, const int* in_sizes, int n_in,
                              void* d_out, int out_size, void* d_ws, size_t ws_size,
                              hipStream_t stream) {
    const float* feats    = (const float*)d_in[0];
    const float* W_in     = (const float*)d_in[1];
    const float* W_blocks = (const float*)d_in[2];
    const float* gamma    = (const float*)d_in[3];
    const float* beta     = (const float*)d_in[4];
    const int*   p2v      = (const int*)d_in[5];
    const int*   nbr      = (const int*)d_in[6];
    const int*   sp       = (const int*)d_in[7];
    float* out = (float*)d_out;
    float* wsf = (float*)d_ws;

    // ---- workspace layout (float offsets), total ~20.0M floats ----
    int*    cnt_v  = (int*)(wsf + 0);              // 250k
    int*    off_v  = (int*)(wsf + 250000);         // 250k
    int*    cnt_s  = (int*)(wsf + 500000);         // 20k
    int*    off_s  = (int*)(wsf + 520000);         // 20k
    int*    psum_v = (int*)(wsf + 540000);         // 256
    int*    psum_s = (int*)(wsf + 541000);         // 256
    int*    pidx_v = (int*)(wsf + 542000);         // 700k
    int*    pidx_s = (int*)(wsf + 1242000);        // 700k
    ushort* voxH   = (ushort*)(wsf + 1942000);     // 2M ush (1M f)
    ushort* voxL   = (ushort*)(wsf + 2942000);     // 2M ush
    ushort* WbH_in = (ushort*)(wsf + 3942000);     // 7168 ush
    ushort* WbL_in = (ushort*)(wsf + 3946000);     // 7168 ush
    ushort* Wb     = (ushort*)(wsf + 3950000);     // 110592 ush
    float*  x      = wsf + 4006000;                // 8M
    ushort* actA   = (ushort*)(wsf + 12006000);    // 8M ush
    ushort* actB   = (ushort*)(wsf + 16006000);    // 8M ush
    // cur_* alias voxH region (dead before k_vox_gather writes voxH)
    int*    cur_v  = (int*)(wsf + 1942000);        // 250k
    int*    cur_s  = (int*)(wsf + 2192000);        // 20k

    const int GP = (N_PTS + 255) / 256;

    hipMemsetAsync(cnt_v, 0, N_VOXELS * sizeof(int), stream);
    hipMemsetAsync(cnt_s, 0, M_SP * sizeof(int), stream);

    k_wprep<<<(4 * 27 * 2 * 64 + 255) / 256, 256, 0, stream>>>(W_blocks, Wb);
    k_wprep_in<<<(7 * 2 * 64 + 255) / 256, 256, 0, stream>>>(W_in, WbH_in, WbL_in);

    // ---- CSR build (fused) ----
    k_hist2<<<GP, 256, 0, stream>>>(p2v, sp, cnt_v, cnt_s);
    k_part2<<<NB_V + NB_S, 256, 0, stream>>>(cnt_v, cnt_s, psum_v, psum_s);
    k_scan2<<<2, 256, 0, stream>>>(psum_v, psum_s);
    k_excl2<<<NB_V + NB_S, 256, 0, stream>>>(cnt_v, cnt_s, psum_v, psum_s,
                                             off_v, off_s, cur_v, cur_s);
    k_fill2<<<GP, 256, 0, stream>>>(p2v, sp, cur_v, cur_s, pidx_v, pidx_s);

    // ---- voxelization (gather mean -> bf16 hi/lo) ----
    k_vox_gather<<<(N_VOXELS + 255) / 256, 256, 0, stream>>>(feats, off_v, cnt_v,
                                                             pidx_v, voxH, voxL);

    // ---- input conv (MFMA, hi/lo ~fp32) ----
    const int CONV_GRID = (N_VOXELS + 127) / 128;
    k_conv_in_m<<<CONV_GRID, 256, 0, stream>>>(voxH, voxL, nbr, WbH_in, WbL_in,
                                               gamma + 0, beta + 0, x, actA);

    // ---- residual blocks ----
    const int WBSZ = 27 * 2 * 64 * 8;
    k_conv32m<<<CONV_GRID, 256, 0, stream>>>(actA, nbr, Wb + 0 * WBSZ,
                                             gamma + 32, beta + 32, nullptr, actB);
    k_conv32m<<<CONV_GRID, 256, 0, stream>>>(actB, nbr, Wb + 1 * WBSZ,
                                             gamma + 64, beta + 64, x, actA);
    k_conv32m<<<CONV_GRID, 256, 0, stream>>>(actA, nbr, Wb + 2 * WBSZ,
                                             gamma + 96, beta + 96, nullptr, actB);
    k_conv32m<<<CONV_GRID, 256, 0, stream>>>(actB, nbr, Wb + 3 * WBSZ,
                                             gamma + 128, beta + 128, x, actA);

    // ---- superpoint mean (gather) ----
    k_sp_gather<<<(M_SP + 3) / 4, 256, 0, stream>>>(actA, off_s, cnt_s,
                                                    pidx_s, out);
}

// Round 10
// 465.104 us; speedup vs baseline: 1.1461x; 1.1461x over previous
//
#include <hip/hip_runtime.h>

#define N_PTS    700000
#define N_VOXELS 250000
#define M_SP     20000
#define EPS_BN   1e-4f
#define NB_V     245   // ceil(N_VOXELS/1024)
#define NB_S     20    // ceil(M_SP/1024)
#define BKT_V    62    // ceil(N_VOXELS/4096)
#define BKT_S    79    // ceil(M_SP/256)

typedef __attribute__((ext_vector_type(8))) short  bf16x8;
typedef __attribute__((ext_vector_type(8))) ushort u16x8;
typedef __attribute__((ext_vector_type(4))) float  f32x4;

__device__ __forceinline__ ushort f2bf(float f) {
    unsigned u = __float_as_uint(f);
    return (ushort)((u + 0x7FFFu + ((u >> 16) & 1u)) >> 16);
}
__device__ __forceinline__ float bf2f(ushort h) {
    return __uint_as_float(((unsigned)h) << 16);
}

// ================= CSR build: histogram =================
__global__ __launch_bounds__(256) void k_hist2(const int* __restrict__ p2v,
                                               const int* __restrict__ sp,
                                               int* __restrict__ cnt_v,
                                               int* __restrict__ cnt_s) {
    int i = blockIdx.x * 256 + threadIdx.x;
    if (i < N_PTS) {
        atomicAdd(&cnt_v[p2v[i]], 1);
        atomicAdd(&cnt_s[sp[i]], 1);
    }
}

// partial sums for BOTH cnt arrays
__global__ __launch_bounds__(256) void k_part2(const int* __restrict__ cnt_v,
                                               const int* __restrict__ cnt_s,
                                               int* __restrict__ psum_v,
                                               int* __restrict__ psum_s) {
    __shared__ int l[256];
    int b = blockIdx.x, t = threadIdx.x;
    const int* cnt; int* psum; int n, bb;
    if (b < NB_V) { cnt = cnt_v; psum = psum_v; n = N_VOXELS; bb = b; }
    else          { cnt = cnt_s; psum = psum_s; n = M_SP;     bb = b - NB_V; }
    int base = bb * 1024 + t * 4;
    int s = 0;
    #pragma unroll
    for (int j = 0; j < 4; ++j) { int i = base + j; if (i < n) s += cnt[i]; }
    l[t] = s; __syncthreads();
    for (int st = 128; st > 0; st >>= 1) {
        if (t < st) l[t] += l[t + st];
        __syncthreads();
    }
    if (t == 0) psum[bb] = l[0];
}

__global__ __launch_bounds__(256) void k_scan2(int* __restrict__ psum_v,
                                               int* __restrict__ psum_s) {
    __shared__ int l[256];
    int t = threadIdx.x;
    int* psum = blockIdx.x == 0 ? psum_v : psum_s;
    int nb    = blockIdx.x == 0 ? NB_V : NB_S;
    int orig = (t < nb) ? psum[t] : 0;
    l[t] = orig; __syncthreads();
    for (int st = 1; st < 256; st <<= 1) {
        int v = (t >= st) ? l[t - st] : 0;
        __syncthreads();
        l[t] += v;
        __syncthreads();
    }
    if (t < nb) psum[t] = l[t] - orig;
}

__global__ __launch_bounds__(256) void k_excl2(const int* __restrict__ cnt_v,
                                               const int* __restrict__ cnt_s,
                                               const int* __restrict__ psum_v,
                                               const int* __restrict__ psum_s,
                                               int* __restrict__ off_v,
                                               int* __restrict__ off_s,
                                               int* __restrict__ cur_v,
                                               int* __restrict__ cur_s) {
    __shared__ int l[256];
    int b = blockIdx.x, t = threadIdx.x;
    const int* cnt; const int* psum; int* off; int* cur; int n, bb;
    if (b < NB_V) { cnt = cnt_v; psum = psum_v; off = off_v; cur = cur_v; n = N_VOXELS; bb = b; }
    else          { cnt = cnt_s; psum = psum_s; off = off_s; cur = cur_s; n = M_SP;     bb = b - NB_V; }
    int base = bb * 1024 + t * 4;
    int c[4]; int s = 0;
    #pragma unroll
    for (int j = 0; j < 4; ++j) {
        int i = base + j;
        c[j] = (i < n) ? cnt[i] : 0;
        s += c[j];
    }
    int orig = s;
    l[t] = s; __syncthreads();
    for (int st = 1; st < 256; st <<= 1) {
        int v = (t >= st) ? l[t - st] : 0;
        __syncthreads();
        l[t] += v;
        __syncthreads();
    }
    int run = l[t] - orig + psum[bb];
    #pragma unroll
    for (int j = 0; j < 4; ++j) {
        int i = base + j;
        if (i < n) { off[i] = run; cur[i] = run; run += c[j]; }
    }
}

// bucket cursors start at the CSR offset of the first key in each bucket
__global__ __launch_bounds__(256) void k_bcur_init(const int* __restrict__ off_v,
                                                   const int* __restrict__ off_s,
                                                   int* __restrict__ bcur_v,
                                                   int* __restrict__ bcur_s) {
    int t = threadIdx.x;
    if (t < BKT_V) bcur_v[t] = off_v[t << 12];
    if (t < BKT_S) bcur_s[t] = off_s[t << 8];
}

// ========== phase A: bin points into buckets (dense, line-friendly writes) ==========
__global__ __launch_bounds__(256) void k_bucket(const int* __restrict__ p2v,
                                                const int* __restrict__ sp,
                                                int* __restrict__ bcur_v,
                                                int* __restrict__ bcur_s,
                                                int2* __restrict__ bufv,
                                                int2* __restrict__ bufs) {
    __shared__ int hv[BKT_V], hs[BKT_S];
    __shared__ int bv[BKT_V], bs[BKT_S];
    const int t = threadIdx.x;
    const int base = blockIdx.x * 1024;
    for (int i = t; i < BKT_V; i += 256) hv[i] = 0;
    for (int i = t; i < BKT_S; i += 256) hs[i] = 0;
    __syncthreads();
    int pv[4], ks[4], rv[4], rs[4];
    #pragma unroll
    for (int j = 0; j < 4; ++j) {
        int i = base + j * 256 + t;
        if (i < N_PTS) {
            pv[j] = p2v[i];
            ks[j] = sp[i];
            rv[j] = atomicAdd(&hv[pv[j] >> 12], 1);
            rs[j] = atomicAdd(&hs[ks[j] >> 8], 1);
        }
    }
    __syncthreads();
    for (int b = t; b < BKT_V; b += 256) bv[b] = atomicAdd(&bcur_v[b], hv[b]);
    for (int b = t; b < BKT_S; b += 256) bs[b] = atomicAdd(&bcur_s[b], hs[b]);
    __syncthreads();
    #pragma unroll
    for (int j = 0; j < 4; ++j) {
        int i = base + j * 256 + t;
        if (i < N_PTS) {
            int2 ev; ev.x = i;     ev.y = pv[j];
            int2 es; es.x = pv[j]; es.y = ks[j];
            bufv[bv[pv[j] >> 12] + rv[j]] = ev;
            bufs[bs[ks[j] >> 8] + rs[j]] = es;
        }
    }
}

// ========== phase B: place within bucket (destination window is L2-resident) ==========
#define PL_SL 4
__global__ __launch_bounds__(256) void k_place(const int* __restrict__ off_v,
                                               const int* __restrict__ off_s,
                                               int* __restrict__ cur_v,
                                               int* __restrict__ cur_s,
                                               const int2* __restrict__ bufv,
                                               const int2* __restrict__ bufs,
                                               int* __restrict__ pidx_v,
                                               int* __restrict__ pidx_s) {
    int blk = blockIdx.x;
    const int2* buf; int* cur; int* pidx; int s, e;
    if (blk < BKT_V * PL_SL) {
        int b = blk / PL_SL;
        s = off_v[b << 12];
        e = ((b + 1) << 12 >= N_VOXELS) ? N_PTS : off_v[(b + 1) << 12];
        buf = bufv; cur = cur_v; pidx = pidx_v;
        int q = blk % PL_SL, len = e - s;
        int s0 = s + (len * q) / PL_SL, e0 = s + (len * (q + 1)) / PL_SL;
        s = s0; e = e0;
    } else {
        blk -= BKT_V * PL_SL;
        int b = blk / PL_SL;
        s = off_s[b << 8];
        e = ((b + 1) << 8 >= M_SP) ? N_PTS : off_s[(b + 1) << 8];
        buf = bufs; cur = cur_s; pidx = pidx_s;
        int q = blk % PL_SL, len = e - s;
        int s0 = s + (len * q) / PL_SL, e0 = s + (len * (q + 1)) / PL_SL;
        s = s0; e = e0;
    }
    for (int i = s + threadIdx.x; i < e; i += 256) {
        int2 en = buf[i];
        pidx[atomicAdd(&cur[en.y], 1)] = en.x;
    }
}

// ================= voxelization: CSR gather mean -> bf16 hi/lo =================
__global__ __launch_bounds__(256) void k_vox_gather(const float* __restrict__ feats,
                                                    const int* __restrict__ off,
                                                    const int* __restrict__ cnt,
                                                    const int* __restrict__ pidx,
                                                    ushort* __restrict__ voxH,
                                                    ushort* __restrict__ voxL) {
    int v = blockIdx.x * 256 + threadIdx.x;
    if (v >= N_VOXELS) return;
    int s = off[v], c = cnt[v];
    float a[6] = {0, 0, 0, 0, 0, 0};
    for (int k = 0; k < c; ++k) {
        int p = pidx[s + k];
        const float2* f = (const float2*)(feats + (size_t)p * 6);
        float2 x0 = f[0], x1 = f[1], x2 = f[2];
        a[0] += x0.x; a[1] += x0.y; a[2] += x1.x;
        a[3] += x1.y; a[4] += x2.x; a[5] += x2.y;
    }
    float inv = 1.0f / (float)max(c, 1);
    u16x8 hv, lv;
    #pragma unroll
    for (int j = 0; j < 6; ++j) {
        float m = a[j] * inv;
        ushort h = f2bf(m);
        hv[j] = h;
        lv[j] = f2bf(m - bf2f(h));
    }
    hv[6] = 0; hv[7] = 0; lv[6] = 0; lv[7] = 0;
    *(u16x8*)(voxH + (size_t)v * 8) = hv;
    *(u16x8*)(voxL + (size_t)v * 8) = lv;
}

// ================= weight pre-pack: conv_in (hi/lo) =================
__global__ __launch_bounds__(256) void k_wprep_in(const float* __restrict__ W,
                                                  ushort* __restrict__ WbH,
                                                  ushort* __restrict__ WbL) {
    int t = blockIdx.x * 256 + threadIdx.x;
    if (t >= 7 * 2 * 64) return;
    int l  = t & 63;
    int nf = (t >> 6) & 1;
    int s7 = t >> 7;
    int g  = l >> 4;
    int c  = nf * 16 + (l & 15);
    int o  = s7 * 4 + g;
    u16x8 hv, lv;
    #pragma unroll
    for (int j = 0; j < 8; ++j) {
        float w = (j < 6 && o < 27) ? W[(o * 6 + j) * 32 + c] : 0.0f;
        ushort h = f2bf(w);
        hv[j] = h;
        lv[j] = f2bf(w - bf2f(h));
    }
    *(u16x8*)(WbH + (size_t)t * 8) = hv;
    *(u16x8*)(WbL + (size_t)t * 8) = lv;
}

// ================= weight pre-pack: conv32m =================
__global__ __launch_bounds__(256) void k_wprep(const float* __restrict__ W,
                                               ushort* __restrict__ Wb) {
    int t = blockIdx.x * 256 + threadIdx.x;
    if (t >= 4 * 27 * 2 * 64) return;
    int l  = t & 63;
    int nf = (t >> 6) & 1;
    int co = t >> 7;
    const float* Wo = W + (size_t)co * 1024;
    int kb = (l >> 4) * 8;
    int c  = nf * 16 + (l & 15);
    u16x8 v;
    #pragma unroll
    for (int j = 0; j < 8; ++j) v[j] = f2bf(Wo[(kb + j) * 32 + c]);
    *(u16x8*)(Wb + (size_t)t * 8) = v;
}

// ================= input conv 6->32 via MFMA (hi/lo split) =================
__global__ __launch_bounds__(256) void k_conv_in_m(const ushort* __restrict__ voxH,
                                                   const ushort* __restrict__ voxL,
                                                   const int* __restrict__ nbr,
                                                   const ushort* __restrict__ WbH,
                                                   const ushort* __restrict__ WbL,
                                                   const float* __restrict__ gamma,
                                                   const float* __restrict__ beta,
                                                   float* __restrict__ x_out,
                                                   ushort* __restrict__ act_out) {
    __shared__ int nl[128][27];
    const int tid = threadIdx.x;
    const int vbase = blockIdx.x * 128;
    for (int i = tid; i < 128 * 27; i += 256) {
        int gi = vbase * 27 + i;
        nl[0][i] = (gi < N_VOXELS * 27) ? nbr[gi] : -1;
    }
    __syncthreads();

    const int l   = tid & 63;
    const int wav = tid >> 6;
    const int r   = l & 15;
    const int g   = l >> 4;
    const int vr0 = wav * 32 + r;
    const int vr1 = vr0 + 16;

    f32x4 a00 = {0,0,0,0}, a01 = {0,0,0,0}, a10 = {0,0,0,0}, a11 = {0,0,0,0};

    for (int s7 = 0; s7 < 7; ++s7) {
        int o = s7 * 4 + g;
        int n0 = (o < 27) ? nl[vr0][o] : -1;
        int n1 = (o < 27) ? nl[vr1][o] : -1;
        bf16x8 A0h = {0,0,0,0,0,0,0,0}, A0l = {0,0,0,0,0,0,0,0};
        bf16x8 A1h = {0,0,0,0,0,0,0,0}, A1l = {0,0,0,0,0,0,0,0};
        if (n0 >= 0) {
            A0h = *(const bf16x8*)(voxH + (size_t)n0 * 8);
            A0l = *(const bf16x8*)(voxL + (size_t)n0 * 8);
        }
        if (n1 >= 0) {
            A1h = *(const bf16x8*)(voxH + (size_t)n1 * 8);
            A1l = *(const bf16x8*)(voxL + (size_t)n1 * 8);
        }
        const bf16x8 B0h = *(const bf16x8*)(WbH + (size_t)(s7 * 2 + 0) * 512 + l * 8);
        const bf16x8 B1h = *(const bf16x8*)(WbH + (size_t)(s7 * 2 + 1) * 512 + l * 8);
        const bf16x8 B0l = *(const bf16x8*)(WbL + (size_t)(s7 * 2 + 0) * 512 + l * 8);
        const bf16x8 B1l = *(const bf16x8*)(WbL + (size_t)(s7 * 2 + 1) * 512 + l * 8);
        a00 = __builtin_amdgcn_mfma_f32_16x16x32_bf16(A0h, B0h, a00, 0, 0, 0);
        a00 = __builtin_amdgcn_mfma_f32_16x16x32_bf16(A0l, B0h, a00, 0, 0, 0);
        a00 = __builtin_amdgcn_mfma_f32_16x16x32_bf16(A0h, B0l, a00, 0, 0, 0);
        a01 = __builtin_amdgcn_mfma_f32_16x16x32_bf16(A0h, B1h, a01, 0, 0, 0);
        a01 = __builtin_amdgcn_mfma_f32_16x16x32_bf16(A0l, B1h, a01, 0, 0, 0);
        a01 = __builtin_amdgcn_mfma_f32_16x16x32_bf16(A0h, B1l, a01, 0, 0, 0);
        a10 = __builtin_amdgcn_mfma_f32_16x16x32_bf16(A1h, B0h, a10, 0, 0, 0);
        a10 = __builtin_amdgcn_mfma_f32_16x16x32_bf16(A1l, B0h, a10, 0, 0, 0);
        a10 = __builtin_amdgcn_mfma_f32_16x16x32_bf16(A1h, B0l, a10, 0, 0, 0);
        a11 = __builtin_amdgcn_mfma_f32_16x16x32_bf16(A1h, B1h, a11, 0, 0, 0);
        a11 = __builtin_amdgcn_mfma_f32_16x16x32_bf16(A1l, B1h, a11, 0, 0, 0);
        a11 = __builtin_amdgcn_mfma_f32_16x16x32_bf16(A1h, B1l, a11, 0, 0, 0);
    }

    const float rs  = rsqrtf(1.f + EPS_BN);
    const float sc0 = gamma[r] * rs,      bb0 = beta[r];
    const float sc1 = gamma[r + 16] * rs, bb1 = beta[r + 16];

    #pragma unroll
    for (int fr = 0; fr < 2; ++fr) {
        #pragma unroll
        for (int j = 0; j < 4; ++j) {
            int vv = vbase + wav * 32 + fr * 16 + g * 4 + j;
            if (vv >= N_VOXELS) continue;
            float v0 = fr ? a10[j] : a00[j];
            float v1 = fr ? a11[j] : a01[j];
            float* xp = x_out + (size_t)vv * 32;
            xp[r]      = v0;
            xp[r + 16] = v1;
            act_out[(size_t)vv * 32 + r]      = f2bf(fmaxf(v0 * sc0 + bb0, 0.f));
            act_out[(size_t)vv * 32 + r + 16] = f2bf(fmaxf(v1 * sc1 + bb1, 0.f));
        }
    }
}

// ================= 32->32 gather conv via bf16 MFMA (round-6 branchy form) =================
__global__ __launch_bounds__(256) void k_conv32m(const ushort* __restrict__ act_in,
                                                 const int* __restrict__ nbr,
                                                 const ushort* __restrict__ Wb,
                                                 const float* __restrict__ gamma,
                                                 const float* __restrict__ beta,
                                                 float* __restrict__ x_inout,
                                                 ushort* __restrict__ act_out,
                                                 const int save_x) {
    __shared__ int nl[128][27];
    const int tid = threadIdx.x;
    const int vbase = blockIdx.x * 128;
    for (int i = tid; i < 128 * 27; i += 256) {
        int gi = vbase * 27 + i;
        nl[0][i] = (gi < N_VOXELS * 27) ? nbr[gi] : -1;
    }
    __syncthreads();

    const int l   = tid & 63;
    const int wav = tid >> 6;
    const int r   = l & 15;
    const int g   = l >> 4;
    const int vr0 = wav * 32 + r;
    const int vr1 = vr0 + 16;

    f32x4 a00 = {0,0,0,0}, a01 = {0,0,0,0}, a10 = {0,0,0,0}, a11 = {0,0,0,0};

    for (int o = 0; o < 27; ++o) {
        int n0 = nl[vr0][o];
        int n1 = nl[vr1][o];
        bf16x8 A0 = {0,0,0,0,0,0,0,0}, A1 = {0,0,0,0,0,0,0,0};
        if (n0 >= 0) A0 = *(const bf16x8*)(act_in + (size_t)n0 * 32 + g * 8);
        if (n1 >= 0) A1 = *(const bf16x8*)(act_in + (size_t)n1 * 32 + g * 8);
        const bf16x8 B0 = *(const bf16x8*)(Wb + (size_t)(o * 2 + 0) * 512 + l * 8);
        const bf16x8 B1 = *(const bf16x8*)(Wb + (size_t)(o * 2 + 1) * 512 + l * 8);
        a00 = __builtin_amdgcn_mfma_f32_16x16x32_bf16(A0, B0, a00, 0, 0, 0);
        a01 = __builtin_amdgcn_mfma_f32_16x16x32_bf16(A0, B1, a01, 0, 0, 0);
        a10 = __builtin_amdgcn_mfma_f32_16x16x32_bf16(A1, B0, a10, 0, 0, 0);
        a11 = __builtin_amdgcn_mfma_f32_16x16x32_bf16(A1, B1, a11, 0, 0, 0);
    }

    const float rs  = rsqrtf(1.f + EPS_BN);
    const float sc0 = gamma[r] * rs,      bb0 = beta[r];
    const float sc1 = gamma[r + 16] * rs, bb1 = beta[r + 16];

    #pragma unroll
    for (int fr = 0; fr < 2; ++fr) {
        #pragma unroll
        for (int j = 0; j < 4; ++j) {
            int vv = vbase + wav * 32 + fr * 16 + g * 4 + j;
            if (vv >= N_VOXELS) continue;
            float v0 = fr ? a10[j] : a00[j];
            float v1 = fr ? a11[j] : a01[j];
            if (x_inout) {
                float* xp = x_inout + (size_t)vv * 32;
                v0 += xp[r];
                v1 += xp[r + 16];
                if (save_x) {
                    xp[r]      = v0;
                    xp[r + 16] = v1;
                }
            }
            act_out[(size_t)vv * 32 + r]      = f2bf(fmaxf(v0 * sc0 + bb0, 0.f));
            act_out[(size_t)vv * 32 + r + 16] = f2bf(fmaxf(v1 * sc1 + bb1, 0.f));
        }
    }
}

// ================= superpoint mean: CSR gather =================
__global__ __launch_bounds__(256) void k_sp_gather(const ushort* __restrict__ act,
                                                   const int* __restrict__ off,
                                                   const int* __restrict__ cnt,
                                                   const int* __restrict__ pidx,
                                                   float* __restrict__ out) {
    int sp = blockIdx.x * 4 + (threadIdx.x >> 6);
    if (sp >= M_SP) return;
    int l   = threadIdx.x & 63;
    int grp = l >> 4;
    int ch2 = l & 15;
    int s = off[sp], c = cnt[sp];
    float a0 = 0.f, a1 = 0.f;
    for (int j = s + grp; j < s + c; j += 4) {
        int v = pidx[j];
        unsigned pk = *(const unsigned*)(act + (size_t)v * 32 + ch2 * 2);
        a0 += __uint_as_float(pk << 16);
        a1 += __uint_as_float(pk & 0xFFFF0000u);
    }
    a0 += __shfl_xor(a0, 16); a1 += __shfl_xor(a1, 16);
    a0 += __shfl_xor(a0, 32); a1 += __shfl_xor(a1, 32);
    if (grp == 0) {
        float inv = 1.0f / (float)max(c, 1);
        *(float2*)(out + (size_t)sp * 32 + ch2 * 2) = make_float2(a0 * inv, a1 * inv);
    }
}

extern "C" void kernel_launch(void* const* d_in, const int* in_sizes, int n_in,
                              void* d_out, int out_size, void* d_ws, size_t ws_size,
                              hipStream_t stream) {
    const float* feats    = (const float*)d_in[0];
    const float* W_in     = (const float*)d_in[1];
    const float* W_blocks = (const float*)d_in[2];
    const float* gamma    = (const float*)d_in[3];
    const float* beta     = (const float*)d_in[4];
    const int*   p2v      = (const int*)d_in[5];
    const int*   nbr      = (const int*)d_in[6];
    const int*   sp       = (const int*)d_in[7];
    float* out = (float*)d_out;
    float* wsf = (float*)d_ws;

    // ---- workspace layout (float offsets), total 18.3M floats = 73.2MB ----
    int*    cnt_v  = (int*)(wsf + 0);              // 250k
    int*    off_v  = (int*)(wsf + 250000);         // 250k
    int*    cnt_s  = (int*)(wsf + 500000);         // 20k
    int*    off_s  = (int*)(wsf + 520000);         // 20k
    int*    psum_v = (int*)(wsf + 540000);         // 245
    int*    psum_s = (int*)(wsf + 541000);         // 20
    int*    cur_v  = (int*)(wsf + 542000);         // 250k
    int*    cur_s  = (int*)(wsf + 792000);         // 20k
    int*    bcur_v = (int*)(wsf + 812000);         // 64
    int*    bcur_s = (int*)(wsf + 813000);         // 96
    int*    pidx_v = (int*)(wsf + 814000);         // 700k
    int*    pidx_s = (int*)(wsf + 1514000);        // 700k
    ushort* WbH_in = (ushort*)(wsf + 2214000);     // 7168 ush
    ushort* WbL_in = (ushort*)(wsf + 2218000);     // 7168 ush
    ushort* Wb     = (ushort*)(wsf + 2222000);     // 110592 ush
    float*  x      = wsf + 2300000;                // 8M (ends 10300000)
    int2*   bufv   = (int2*)(wsf + 2300000);       // alias x: dead before conv_in writes x
    int2*   bufs   = (int2*)(wsf + 3700000);       // alias x
    ushort* actA   = (ushort*)(wsf + 10300000);    // 8M ush (ends 14300000)
    ushort* actB   = (ushort*)(wsf + 14300000);    // 8M ush (ends 18300000)
    ushort* voxH   = (ushort*)(wsf + 14300000);    // alias actB: dead after conv_in
    ushort* voxL   = (ushort*)(wsf + 15300000);    // alias actB

    const int GP = (N_PTS + 255) / 256;

    hipMemsetAsync(cnt_v, 0, N_VOXELS * sizeof(int), stream);
    hipMemsetAsync(cnt_s, 0, M_SP * sizeof(int), stream);

    k_wprep<<<(4 * 27 * 2 * 64 + 255) / 256, 256, 0, stream>>>(W_blocks, Wb);
    k_wprep_in<<<(7 * 2 * 64 + 255) / 256, 256, 0, stream>>>(W_in, WbH_in, WbL_in);

    // ---- CSR build ----
    k_hist2<<<GP, 256, 0, stream>>>(p2v, sp, cnt_v, cnt_s);
    k_part2<<<NB_V + NB_S, 256, 0, stream>>>(cnt_v, cnt_s, psum_v, psum_s);
    k_scan2<<<2, 256, 0, stream>>>(psum_v, psum_s);
    k_excl2<<<NB_V + NB_S, 256, 0, stream>>>(cnt_v, cnt_s, psum_v, psum_s,
                                             off_v, off_s, cur_v, cur_s);
    k_bcur_init<<<1, 256, 0, stream>>>(off_v, off_s, bcur_v, bcur_s);
    k_bucket<<<(N_PTS + 1023) / 1024, 256, 0, stream>>>(p2v, sp, bcur_v, bcur_s,
                                                        bufv, bufs);
    k_place<<<(BKT_V + BKT_S) * PL_SL, 256, 0, stream>>>(off_v, off_s, cur_v, cur_s,
                                                         bufv, bufs, pidx_v, pidx_s);

    // ---- voxelization (gather mean -> bf16 hi/lo) ----
    k_vox_gather<<<(N_VOXELS + 255) / 256, 256, 0, stream>>>(feats, off_v, cnt_v,
                                                             pidx_v, voxH, voxL);

    // ---- input conv (MFMA, hi/lo ~fp32) ----
    const int CONV_GRID = (N_VOXELS + 127) / 128;
    k_conv_in_m<<<CONV_GRID, 256, 0, stream>>>(voxH, voxL, nbr, WbH_in, WbL_in,
                                               gamma + 0, beta + 0, x, actA);

    // ---- residual blocks ----
    const int WBSZ = 27 * 2 * 64 * 8;
    k_conv32m<<<CONV_GRID, 256, 0, stream>>>(actA, nbr, Wb + 0 * WBSZ,
                                             gamma + 32, beta + 32, nullptr, actB, 0);
    k_conv32m<<<CONV_GRID, 256, 0, stream>>>(actB, nbr, Wb + 1 * WBSZ,
                                             gamma + 64, beta + 64, x, actA, 1);
    k_conv32m<<<CONV_GRID, 256, 0, stream>>>(actA, nbr, Wb + 2 * WBSZ,
                                             gamma + 96, beta + 96, nullptr, actB, 0);
    k_conv32m<<<CONV_GRID, 256, 0, stream>>>(actB, nbr, Wb + 3 * WBSZ,
                                             gamma + 128, beta + 128, x, actA, 0);

    // ---- superpoint mean (gather) ----
    k_sp_gather<<<(M_SP + 3) / 4, 256, 0, stream>>>(actA, off_s, cnt_s,
                                                    pidx_s, out);
}

// Round 14
// 386.136 us; speedup vs baseline: 1.3804x; 1.2045x over previous
//
#include <hip/hip_runtime.h>

#define N_PTS    700000
#define N_VOXELS 250000
#define M_SP     20000
#define EPS_BN   1e-4f
#define VSH      11
#define SSH      7
#define BKT_V    123   // ceil(N_VOXELS/2048)
#define BKT_S    157   // ceil(M_SP/128)

typedef __attribute__((ext_vector_type(8))) short  bf16x8;
typedef __attribute__((ext_vector_type(8))) ushort u16x8;
typedef __attribute__((ext_vector_type(4))) float  f32x4;

__device__ __forceinline__ ushort f2bf(float f) {
    unsigned u = __float_as_uint(f);
    return (ushort)((u + 0x7FFFu + ((u >> 16) & 1u)) >> 16);
}
__device__ __forceinline__ float bf2f(ushort h) {
    return __uint_as_float(((unsigned)h) << 16);
}

// ========== bucket-count: LDS histogram of bucket ids, few global atomics ==========
__global__ __launch_bounds__(256) void k_bktcnt(const int* __restrict__ p2v,
                                                const int* __restrict__ sp,
                                                int* __restrict__ bkcnt_v,
                                                int* __restrict__ bkcnt_s) {
    __shared__ int hv[BKT_V], hs[BKT_S];
    const int t = threadIdx.x;
    const int base = blockIdx.x * 1024;
    for (int i = t; i < BKT_V; i += 256) hv[i] = 0;
    for (int i = t; i < BKT_S; i += 256) hs[i] = 0;
    __syncthreads();
    #pragma unroll
    for (int j = 0; j < 4; ++j) {
        int i = base + j * 256 + t;
        if (i < N_PTS) {
            atomicAdd(&hv[p2v[i] >> VSH], 1);
            atomicAdd(&hs[sp[i] >> SSH], 1);
        }
    }
    __syncthreads();
    for (int b = t; b < BKT_V; b += 256) if (hv[b]) atomicAdd(&bkcnt_v[b], hv[b]);
    for (int b = t; b < BKT_S; b += 256) if (hs[b]) atomicAdd(&bkcnt_s[b], hs[b]);
}

// ========== scan bucket counts -> bases + cursors (block0: v, block1: s) ==========
__global__ __launch_bounds__(256) void k_bktscan(const int* __restrict__ bkcnt_v,
                                                 const int* __restrict__ bkcnt_s,
                                                 int* __restrict__ bkbase_v,
                                                 int* __restrict__ bkbase_s,
                                                 int* __restrict__ bcur_v,
                                                 int* __restrict__ bcur_s) {
    __shared__ int l[256];
    int t = threadIdx.x;
    const int* cntb; int* base; int* cur; int nb;
    if (blockIdx.x == 0) { cntb = bkcnt_v; base = bkbase_v; cur = bcur_v; nb = BKT_V; }
    else                 { cntb = bkcnt_s; base = bkbase_s; cur = bcur_s; nb = BKT_S; }
    int orig = (t < nb) ? cntb[t] : 0;
    l[t] = orig; __syncthreads();
    for (int st = 1; st < 256; st <<= 1) {
        int v = (t >= st) ? l[t - st] : 0;
        __syncthreads();
        l[t] += v;
        __syncthreads();
    }
    if (t < nb) { int b = l[t] - orig; base[t] = b; cur[t] = b; }
    if (t == 0) base[nb] = N_PTS;
}

// ========== bin points into buckets (dense, line-friendly record writes) ==========
__global__ __launch_bounds__(256) void k_bucket(const int* __restrict__ p2v,
                                                const int* __restrict__ sp,
                                                int* __restrict__ bcur_v,
                                                int* __restrict__ bcur_s,
                                                int2* __restrict__ bufv,
                                                int2* __restrict__ bufs) {
    __shared__ int hv[BKT_V], hs[BKT_S];
    __shared__ int bv[BKT_V], bs[BKT_S];
    const int t = threadIdx.x;
    const int base = blockIdx.x * 1024;
    for (int i = t; i < BKT_V; i += 256) hv[i] = 0;
    for (int i = t; i < BKT_S; i += 256) hs[i] = 0;
    __syncthreads();
    int pv[4], ks[4], rv[4], rs[4];
    #pragma unroll
    for (int j = 0; j < 4; ++j) {
        int i = base + j * 256 + t;
        if (i < N_PTS) {
            pv[j] = p2v[i];
            ks[j] = sp[i];
            rv[j] = atomicAdd(&hv[pv[j] >> VSH], 1);
            rs[j] = atomicAdd(&hs[ks[j] >> SSH], 1);
        }
    }
    __syncthreads();
    for (int b = t; b < BKT_V; b += 256) bv[b] = hv[b] ? atomicAdd(&bcur_v[b], hv[b]) : 0;
    for (int b = t; b < BKT_S; b += 256) bs[b] = hs[b] ? atomicAdd(&bcur_s[b], hs[b]) : 0;
    __syncthreads();
    #pragma unroll
    for (int j = 0; j < 4; ++j) {
        int i = base + j * 256 + t;
        if (i < N_PTS) {
            int2 ev; ev.x = i;     ev.y = pv[j];
            int2 es; es.x = pv[j]; es.y = ks[j];
            bufv[bv[pv[j] >> VSH] + rv[j]] = ev;
            bufs[bs[ks[j] >> SSH] + rs[j]] = es;
        }
    }
}

// ========== finalize: per-bucket hist + scan + cnt/off + place, all in one block ==========
__global__ __launch_bounds__(256) void k_fin(const int* __restrict__ bkbase_v,
                                             const int* __restrict__ bkbase_s,
                                             const int2* __restrict__ bufv,
                                             const int2* __restrict__ bufs,
                                             int* __restrict__ pidx_v,
                                             int* __restrict__ pidx_s,
                                             int* __restrict__ cnt_v,
                                             int* __restrict__ cnt_s,
                                             int* __restrict__ off_v,
                                             int* __restrict__ off_s) {
    __shared__ int hist[1 << VSH];
    __shared__ int lsum[256];
    const int blk = blockIdx.x, t = threadIdx.x;
    const int2* buf; int* pidx; int* cnt; int* off;
    int kbase, nk, s, e;
    if (blk < BKT_V) {
        buf = bufv; pidx = pidx_v; cnt = cnt_v; off = off_v;
        kbase = blk << VSH; nk = min(1 << VSH, N_VOXELS - kbase);
        s = bkbase_v[blk]; e = bkbase_v[blk + 1];
    } else {
        int b = blk - BKT_V;
        buf = bufs; pidx = pidx_s; cnt = cnt_s; off = off_s;
        kbase = b << SSH; nk = min(1 << SSH, M_SP - kbase);
        s = bkbase_s[b]; e = bkbase_s[b + 1];
    }
    for (int i = t; i < nk; i += 256) hist[i] = 0;
    __syncthreads();
    for (int i = s + t; i < e; i += 256) atomicAdd(&hist[buf[i].y - kbase], 1);
    __syncthreads();
    // block scan of hist[0..nk) (nk <= 2048), 8 keys/thread, fully unrolled
    int c[8], ls = 0;
    #pragma unroll
    for (int j = 0; j < 8; ++j) {
        int idx = t * 8 + j;
        c[j] = (idx < nk) ? hist[idx] : 0;
        ls += c[j];
    }
    lsum[t] = ls;
    __syncthreads();
    for (int st = 1; st < 256; st <<= 1) {
        int v = (t >= st) ? lsum[t - st] : 0;
        __syncthreads();
        lsum[t] += v;
        __syncthreads();
    }
    int run = lsum[t] - ls;
    #pragma unroll
    for (int j = 0; j < 8; ++j) {
        int idx = t * 8 + j;
        if (idx < nk) {
            off[kbase + idx] = s + run;
            cnt[kbase + idx] = c[j];
            hist[idx] = run;
            run += c[j];
        }
    }
    __syncthreads();
    // place within this bucket's window (single block -> L2-local writes)
    for (int i = s + t; i < e; i += 256) {
        int2 en = buf[i];
        int pos = atomicAdd(&hist[en.y - kbase], 1);
        pidx[s + pos] = en.x;
    }
}

// ================= voxelization: CSR gather mean -> bf16 hi/lo =================
__global__ __launch_bounds__(256) void k_vox_gather(const float* __restrict__ feats,
                                                    const int* __restrict__ off,
                                                    const int* __restrict__ cnt,
                                                    const int* __restrict__ pidx,
                                                    ushort* __restrict__ voxH,
                                                    ushort* __restrict__ voxL) {
    int v = blockIdx.x * 256 + threadIdx.x;
    if (v >= N_VOXELS) return;
    int s = off[v], c = cnt[v];
    float a[6] = {0, 0, 0, 0, 0, 0};
    for (int k = 0; k < c; ++k) {
        int p = pidx[s + k];
        const float2* f = (const float2*)(feats + (size_t)p * 6);
        float2 x0 = f[0], x1 = f[1], x2 = f[2];
        a[0] += x0.x; a[1] += x0.y; a[2] += x1.x;
        a[3] += x1.y; a[4] += x2.x; a[5] += x2.y;
    }
    float inv = 1.0f / (float)max(c, 1);
    u16x8 hv, lv;
    #pragma unroll
    for (int j = 0; j < 6; ++j) {
        float m = a[j] * inv;
        ushort h = f2bf(m);
        hv[j] = h;
        lv[j] = f2bf(m - bf2f(h));
    }
    hv[6] = 0; hv[7] = 0; lv[6] = 0; lv[7] = 0;
    *(u16x8*)(voxH + (size_t)v * 8) = hv;
    *(u16x8*)(voxL + (size_t)v * 8) = lv;
}

// ================= weight pre-pack: conv_in (hi/lo) =================
__global__ __launch_bounds__(256) void k_wprep_in(const float* __restrict__ W,
                                                  ushort* __restrict__ WbH,
                                                  ushort* __restrict__ WbL) {
    int t = blockIdx.x * 256 + threadIdx.x;
    if (t >= 7 * 2 * 64) return;
    int l  = t & 63;
    int nf = (t >> 6) & 1;
    int s7 = t >> 7;
    int g  = l >> 4;
    int c  = nf * 16 + (l & 15);
    int o  = s7 * 4 + g;
    u16x8 hv, lv;
    #pragma unroll
    for (int j = 0; j < 8; ++j) {
        float w = (j < 6 && o < 27) ? W[(o * 6 + j) * 32 + c] : 0.0f;
        ushort h = f2bf(w);
        hv[j] = h;
        lv[j] = f2bf(w - bf2f(h));
    }
    *(u16x8*)(WbH + (size_t)t * 8) = hv;
    *(u16x8*)(WbL + (size_t)t * 8) = lv;
}

// ================= weight pre-pack: conv32m =================
__global__ __launch_bounds__(256) void k_wprep(const float* __restrict__ W,
                                               ushort* __restrict__ Wb) {
    int t = blockIdx.x * 256 + threadIdx.x;
    if (t >= 4 * 27 * 2 * 64) return;
    int l  = t & 63;
    int nf = (t >> 6) & 1;
    int co = t >> 7;
    const float* Wo = W + (size_t)co * 1024;
    int kb = (l >> 4) * 8;
    int c  = nf * 16 + (l & 15);
    u16x8 v;
    #pragma unroll
    for (int j = 0; j < 8; ++j) v[j] = f2bf(Wo[(kb + j) * 32 + c]);
    *(u16x8*)(Wb + (size_t)t * 8) = v;
}

// ================= input conv 6->32 via MFMA (hi/lo split) =================
__global__ __launch_bounds__(256) void k_conv_in_m(const ushort* __restrict__ voxH,
                                                   const ushort* __restrict__ voxL,
                                                   const int* __restrict__ nbr,
                                                   const ushort* __restrict__ WbH,
                                                   const ushort* __restrict__ WbL,
                                                   const float* __restrict__ gamma,
                                                   const float* __restrict__ beta,
                                                   float* __restrict__ x_out,
                                                   ushort* __restrict__ act_out) {
    __shared__ int nl[128][27];
    const int tid = threadIdx.x;
    const int vbase = blockIdx.x * 128;
    for (int i = tid; i < 128 * 27; i += 256) {
        int gi = vbase * 27 + i;
        nl[0][i] = (gi < N_VOXELS * 27) ? nbr[gi] : -1;
    }
    __syncthreads();

    const int l   = tid & 63;
    const int wav = tid >> 6;
    const int r   = l & 15;
    const int g   = l >> 4;
    const int vr0 = wav * 32 + r;
    const int vr1 = vr0 + 16;

    f32x4 a00 = {0,0,0,0}, a01 = {0,0,0,0}, a10 = {0,0,0,0}, a11 = {0,0,0,0};

    for (int s7 = 0; s7 < 7; ++s7) {
        int o = s7 * 4 + g;
        int n0 = (o < 27) ? nl[vr0][o] : -1;
        int n1 = (o < 27) ? nl[vr1][o] : -1;
        bf16x8 A0h = {0,0,0,0,0,0,0,0}, A0l = {0,0,0,0,0,0,0,0};
        bf16x8 A1h = {0,0,0,0,0,0,0,0}, A1l = {0,0,0,0,0,0,0,0};
        if (n0 >= 0) {
            A0h = *(const bf16x8*)(voxH + (size_t)n0 * 8);
            A0l = *(const bf16x8*)(voxL + (size_t)n0 * 8);
        }
        if (n1 >= 0) {
            A1h = *(const bf16x8*)(voxH + (size_t)n1 * 8);
            A1l = *(const bf16x8*)(voxL + (size_t)n1 * 8);
        }
        const bf16x8 B0h = *(const bf16x8*)(WbH + (size_t)(s7 * 2 + 0) * 512 + l * 8);
        const bf16x8 B1h = *(const bf16x8*)(WbH + (size_t)(s7 * 2 + 1) * 512 + l * 8);
        const bf16x8 B0l = *(const bf16x8*)(WbL + (size_t)(s7 * 2 + 0) * 512 + l * 8);
        const bf16x8 B1l = *(const bf16x8*)(WbL + (size_t)(s7 * 2 + 1) * 512 + l * 8);
        a00 = __builtin_amdgcn_mfma_f32_16x16x32_bf16(A0h, B0h, a00, 0, 0, 0);
        a00 = __builtin_amdgcn_mfma_f32_16x16x32_bf16(A0l, B0h, a00, 0, 0, 0);
        a00 = __builtin_amdgcn_mfma_f32_16x16x32_bf16(A0h, B0l, a00, 0, 0, 0);
        a01 = __builtin_amdgcn_mfma_f32_16x16x32_bf16(A0h, B1h, a01, 0, 0, 0);
        a01 = __builtin_amdgcn_mfma_f32_16x16x32_bf16(A0l, B1h, a01, 0, 0, 0);
        a01 = __builtin_amdgcn_mfma_f32_16x16x32_bf16(A0h, B1l, a01, 0, 0, 0);
        a10 = __builtin_amdgcn_mfma_f32_16x16x32_bf16(A1h, B0h, a10, 0, 0, 0);
        a10 = __builtin_amdgcn_mfma_f32_16x16x32_bf16(A1l, B0h, a10, 0, 0, 0);
        a10 = __builtin_amdgcn_mfma_f32_16x16x32_bf16(A1h, B0l, a10, 0, 0, 0);
        a11 = __builtin_amdgcn_mfma_f32_16x16x32_bf16(A1h, B1h, a11, 0, 0, 0);
        a11 = __builtin_amdgcn_mfma_f32_16x16x32_bf16(A1l, B1h, a11, 0, 0, 0);
        a11 = __builtin_amdgcn_mfma_f32_16x16x32_bf16(A1h, B1l, a11, 0, 0, 0);
    }

    const float rs  = rsqrtf(1.f + EPS_BN);
    const float sc0 = gamma[r] * rs,      bb0 = beta[r];
    const float sc1 = gamma[r + 16] * rs, bb1 = beta[r + 16];

    #pragma unroll
    for (int fr = 0; fr < 2; ++fr) {
        #pragma unroll
        for (int j = 0; j < 4; ++j) {
            int vv = vbase + wav * 32 + fr * 16 + g * 4 + j;
            if (vv >= N_VOXELS) continue;
            float v0 = fr ? a10[j] : a00[j];
            float v1 = fr ? a11[j] : a01[j];
            float* xp = x_out + (size_t)vv * 32;
            xp[r]      = v0;
            xp[r + 16] = v1;
            act_out[(size_t)vv * 32 + r]      = f2bf(fmaxf(v0 * sc0 + bb0, 0.f));
            act_out[(size_t)vv * 32 + r + 16] = f2bf(fmaxf(v1 * sc1 + bb1, 0.f));
        }
    }
}

// ================= 32->32 gather conv via bf16 MFMA =================
__global__ __launch_bounds__(256) void k_conv32m(const ushort* __restrict__ act_in,
                                                 const int* __restrict__ nbr,
                                                 const ushort* __restrict__ Wb,
                                                 const float* __restrict__ gamma,
                                                 const float* __restrict__ beta,
                                                 float* __restrict__ x_inout,
                                                 ushort* __restrict__ act_out,
                                                 const int save_x) {
    __shared__ int nl[128][27];
    const int tid = threadIdx.x;
    const int vbase = blockIdx.x * 128;
    for (int i = tid; i < 128 * 27; i += 256) {
        int gi = vbase * 27 + i;
        nl[0][i] = (gi < N_VOXELS * 27) ? nbr[gi] : -1;
    }
    __syncthreads();

    const int l   = tid & 63;
    const int wav = tid >> 6;
    const int r   = l & 15;
    const int g   = l >> 4;
    const int vr0 = wav * 32 + r;
    const int vr1 = vr0 + 16;

    f32x4 a00 = {0,0,0,0}, a01 = {0,0,0,0}, a10 = {0,0,0,0}, a11 = {0,0,0,0};

    for (int o = 0; o < 27; ++o) {
        int n0 = nl[vr0][o];
        int n1 = nl[vr1][o];
        bf16x8 A0 = {0,0,0,0,0,0,0,0}, A1 = {0,0,0,0,0,0,0,0};
        if (n0 >= 0) A0 = *(const bf16x8*)(act_in + (size_t)n0 * 32 + g * 8);
        if (n1 >= 0) A1 = *(const bf16x8*)(act_in + (size_t)n1 * 32 + g * 8);
        const bf16x8 B0 = *(const bf16x8*)(Wb + (size_t)(o * 2 + 0) * 512 + l * 8);
        const bf16x8 B1 = *(const bf16x8*)(Wb + (size_t)(o * 2 + 1) * 512 + l * 8);
        a00 = __builtin_amdgcn_mfma_f32_16x16x32_bf16(A0, B0, a00, 0, 0, 0);
        a01 = __builtin_amdgcn_mfma_f32_16x16x32_bf16(A0, B1, a01, 0, 0, 0);
        a10 = __builtin_amdgcn_mfma_f32_16x16x32_bf16(A1, B0, a10, 0, 0, 0);
        a11 = __builtin_amdgcn_mfma_f32_16x16x32_bf16(A1, B1, a11, 0, 0, 0);
    }

    const float rs  = rsqrtf(1.f + EPS_BN);
    const float sc0 = gamma[r] * rs,      bb0 = beta[r];
    const float sc1 = gamma[r + 16] * rs, bb1 = beta[r + 16];

    #pragma unroll
    for (int fr = 0; fr < 2; ++fr) {
        #pragma unroll
        for (int j = 0; j < 4; ++j) {
            int vv = vbase + wav * 32 + fr * 16 + g * 4 + j;
            if (vv >= N_VOXELS) continue;
            float v0 = fr ? a10[j] : a00[j];
            float v1 = fr ? a11[j] : a01[j];
            if (x_inout) {
                float* xp = x_inout + (size_t)vv * 32;
                v0 += xp[r];
                v1 += xp[r + 16];
                if (save_x) {
                    xp[r]      = v0;
                    xp[r + 16] = v1;
                }
            }
            act_out[(size_t)vv * 32 + r]      = f2bf(fmaxf(v0 * sc0 + bb0, 0.f));
            act_out[(size_t)vv * 32 + r + 16] = f2bf(fmaxf(v1 * sc1 + bb1, 0.f));
        }
    }
}

// ================= superpoint mean: CSR gather =================
__global__ __launch_bounds__(256) void k_sp_gather(const ushort* __restrict__ act,
                                                   const int* __restrict__ off,
                                                   const int* __restrict__ cnt,
                                                   const int* __restrict__ pidx,
                                                   float* __restrict__ out) {
    int sp = blockIdx.x * 4 + (threadIdx.x >> 6);
    if (sp >= M_SP) return;
    int l   = threadIdx.x & 63;
    int grp = l >> 4;
    int ch2 = l & 15;
    int s = off[sp], c = cnt[sp];
    float a0 = 0.f, a1 = 0.f;
    for (int j = s + grp; j < s + c; j += 4) {
        int v = pidx[j];
        unsigned pk = *(const unsigned*)(act + (size_t)v * 32 + ch2 * 2);
        a0 += __uint_as_float(pk << 16);
        a1 += __uint_as_float(pk & 0xFFFF0000u);
    }
    a0 += __shfl_xor(a0, 16); a1 += __shfl_xor(a1, 16);
    a0 += __shfl_xor(a0, 32); a1 += __shfl_xor(a1, 32);
    if (grp == 0) {
        float inv = 1.0f / (float)max(c, 1);
        *(float2*)(out + (size_t)sp * 32 + ch2 * 2) = make_float2(a0 * inv, a1 * inv);
    }
}

extern "C" void kernel_launch(void* const* d_in, const int* in_sizes, int n_in,
                              void* d_out, int out_size, void* d_ws, size_t ws_size,
                              hipStream_t stream) {
    const float* feats    = (const float*)d_in[0];
    const float* W_in     = (const float*)d_in[1];
    const float* W_blocks = (const float*)d_in[2];
    const float* gamma    = (const float*)d_in[3];
    const float* beta     = (const float*)d_in[4];
    const int*   p2v      = (const int*)d_in[5];
    const int*   nbr      = (const int*)d_in[6];
    const int*   sp       = (const int*)d_in[7];
    float* out = (float*)d_out;
    float* wsf = (float*)d_ws;

    // ---- workspace layout (float offsets), total ~18.0M floats = 72MB ----
    int*    cnt_v    = (int*)(wsf + 0);            // 250k
    int*    off_v    = (int*)(wsf + 250000);       // 250k
    int*    cnt_s    = (int*)(wsf + 500000);       // 20k
    int*    off_s    = (int*)(wsf + 520000);       // 20k
    int*    bkcnt_v  = (int*)(wsf + 540000);       // 123 } contiguous for one memset
    int*    bkcnt_s  = (int*)(wsf + 540123);       // 157 }
    int*    bkbase_v = (int*)(wsf + 541000);       // 124
    int*    bkbase_s = (int*)(wsf + 541200);       // 158
    int*    bcur_v   = (int*)(wsf + 541400);       // 123
    int*    bcur_s   = (int*)(wsf + 541600);       // 157
    int*    pidx_v   = (int*)(wsf + 542000);       // 700k
    int*    pidx_s   = (int*)(wsf + 1242000);      // 700k
    ushort* WbH_in   = (ushort*)(wsf + 1942000);   // 7168 ush
    ushort* WbL_in   = (ushort*)(wsf + 1946000);   // 7168 ush
    ushort* Wb       = (ushort*)(wsf + 1950000);   // 110592 ush
    float*  x        = wsf + 2010000;              // 8M (ends 10010000)
    int2*   bufv     = (int2*)(wsf + 2010000);     // alias x: dead before conv_in writes x
    int2*   bufs     = (int2*)(wsf + 3500000);     // alias x
    ushort* actA     = (ushort*)(wsf + 10010000);  // 8M ush (ends 14010000)
    ushort* actB     = (ushort*)(wsf + 14010000);  // 8M ush (ends 18010000)
    ushort* voxH     = (ushort*)(wsf + 14010000);  // alias actB: dead after conv_in
    ushort* voxL     = (ushort*)(wsf + 15010000);  // alias actB

    const int GB = (N_PTS + 1023) / 1024;

    hipMemsetAsync(bkcnt_v, 0, (BKT_V + BKT_S) * sizeof(int), stream);

    k_wprep<<<(4 * 27 * 2 * 64 + 255) / 256, 256, 0, stream>>>(W_blocks, Wb);
    k_wprep_in<<<(7 * 2 * 64 + 255) / 256, 256, 0, stream>>>(W_in, WbH_in, WbL_in);

    // ---- CSR build (bucketed, LDS-local scatters) ----
    k_bktcnt<<<GB, 256, 0, stream>>>(p2v, sp, bkcnt_v, bkcnt_s);
    k_bktscan<<<2, 256, 0, stream>>>(bkcnt_v, bkcnt_s, bkbase_v, bkbase_s,
                                     bcur_v, bcur_s);
    k_bucket<<<GB, 256, 0, stream>>>(p2v, sp, bcur_v, bcur_s, bufv, bufs);
    k_fin<<<BKT_V + BKT_S, 256, 0, stream>>>(bkbase_v, bkbase_s, bufv, bufs,
                                             pidx_v, pidx_s, cnt_v, cnt_s,
                                             off_v, off_s);

    // ---- voxelization (gather mean -> bf16 hi/lo) ----
    k_vox_gather<<<(N_VOXELS + 255) / 256, 256, 0, stream>>>(feats, off_v, cnt_v,
                                                             pidx_v, voxH, voxL);

    // ---- input conv (MFMA, hi/lo ~fp32) ----
    const int CONV_GRID = (N_VOXELS + 127) / 128;
    k_conv_in_m<<<CONV_GRID, 256, 0, stream>>>(voxH, voxL, nbr, WbH_in, WbL_in,
                                               gamma + 0, beta + 0, x, actA);

    // ---- residual blocks ----
    const int WBSZ = 27 * 2 * 64 * 8;
    k_conv32m<<<CONV_GRID, 256, 0, stream>>>(actA, nbr, Wb + 0 * WBSZ,
                                             gamma + 32, beta + 32, nullptr, actB, 0);
    k_conv32m<<<CONV_GRID, 256, 0, stream>>>(actB, nbr, Wb + 1 * WBSZ,
                                             gamma + 64, beta + 64, x, actA, 1);
    k_conv32m<<<CONV_GRID, 256, 0, stream>>>(actA, nbr, Wb + 2 * WBSZ,
                                             gamma + 96, beta + 96, nullptr, actB, 0);
    k_conv32m<<<CONV_GRID, 256, 0, stream>>>(actB, nbr, Wb + 3 * WBSZ,
                                             gamma + 128, beta + 128, x, actA, 0);

    // ---- superpoint mean (gather) ----
    k_sp_gather<<<(M_SP + 3) / 4, 256, 0, stream>>>(actA, off_s, cnt_s,
                                                    pidx_s, out);
}